// Round 2
// baseline (76.073 us; speedup 1.0000x reference)
//
#include <hip/hip_runtime.h>
#include <math.h>

#define LL 2048
#define LSHIFT 11
#define LMASK 2047
#define NTOT (LL * LL)

// d_profit = fl(fl(coop/5)*3.8).  For coop in 0..5, fl(coop/5) == coop*0.2f
// bit-exactly (verified case-by-case), so two mults replace the divide.
__device__ __forceinline__ float dprof(int coop) {
    return __fmul_rn(__fmul_rn((float)coop, 0.2f), 3.8f);
}

// greedy action + q_new chain, exact per-op f32 to match reference
__device__ __forceinline__ void qstep(int A, float4 q, float trx, float try_,
                                      float profit, float& qn, int& Bact) {
    float qa0 = A ? q.z : q.x;
    float qa1 = A ? q.w : q.y;
    float mx = fmaxf(qa0, qa1);
    float v0 = __fadd_rn(qa0 == mx ? 1.0f : -1.0e9f, trx);
    float v1 = __fadd_rn(qa1 == mx ? 1.0f : -1.0e9f, try_);
    Bact = (v1 > v0) ? 1 : 0;   // argmax, first occurrence on ties
    // EPSILON = -1.0, eps_rand in [0,1) -> eps_mask always true -> B = greedy
    float qb0 = Bact ? q.z : q.x;
    float qb1 = Bact ? q.w : q.y;
    float mn = fmaxf(qb0, qb1);                 // max_a' Q_old[n, B, a']
    float qold = A ? (Bact ? q.w : q.z) : (Bact ? q.y : q.x);
    float a1 = __fmul_rn(0.8f, mn);
    float a2 = __fadd_rn(profit, a1);
    float a3 = __fsub_rn(a2, qold);
    float a4 = __fmul_rn(0.8f, a3);
    qn = __fadd_rn(qold, a4);
}

// ---------- kernel 1: payoff stencil + greedy + Q update, 4 cells/thread ----------

__global__ __launch_bounds__(256) void k_payoff_q(
    const int* __restrict__ type, const float* __restrict__ Q,
    const float* __restrict__ tie, float* __restrict__ outQ,
    float* __restrict__ outP, float* __restrict__ p2w,
    unsigned char* __restrict__ Bw, int use_ws)
{
    int t4 = blockIdx.x * 256 + threadIdx.x;     // 0 .. N/4-1
    int i  = t4 >> 9;                            // row (512 groups of 4 per row)
    int j0 = (t4 & 511) << 2;                    // col base, multiple of 4
    int im  = (i - 1) & LMASK, ip  = (i + 1) & LMASK;
    int im2 = (i - 2) & LMASK, ip2 = (i + 2) & LMASK;
    int jm4 = (j0 - 4) & LMASK, jp4 = (j0 + 4) & LMASK;
    const int4* T4 = (const int4*)type;
#define ROW4(r, c) T4[((((r) << LSHIFT) | (c)) >> 2)]
    int4 uu4 = ROW4(im2, j0);
    int4 upm = ROW4(im, jm4), upc = ROW4(im, j0), upp = ROW4(im, jp4);
    int4 crm = ROW4(i,  jm4), crc = ROW4(i,  j0), crp = ROW4(i,  jp4);
    int4 dnm = ROW4(ip, jm4), dnc = ROW4(ip, j0), dnp = ROW4(ip, jp4);
    int4 dd4 = ROW4(ip2, j0);
#undef ROW4
    int cc[8] = {crm.z, crm.w, crc.x, crc.y, crc.z, crc.w, crp.x, crp.y}; // cols j0-2..j0+5
    int up[6] = {upm.w, upc.x, upc.y, upc.z, upc.w, upp.x};               // cols j0-1..j0+4
    int dn[6] = {dnm.w, dnc.x, dnc.y, dnc.z, dnc.w, dnp.x};
    int uu[4] = {uu4.x, uu4.y, uu4.z, uu4.w};
    int dd[4] = {dd4.x, dd4.y, dd4.z, dd4.w};

    int n0 = (i << LSHIFT) | j0;
    const float4* Q4 = (const float4*)Q;
    float4 q[4] = {Q4[n0], Q4[n0 + 1], Q4[n0 + 2], Q4[n0 + 3]};
    const float4* TI = (const float4*)tie;       // 2 floats/cell -> float4 = 2 cells
    float4 ta = TI[t4 * 2], tb = TI[t4 * 2 + 1];
    float trx[4] = {ta.x, ta.z, tb.x, tb.z};
    float try_[4] = {ta.y, ta.w, tb.y, tb.w};

    float4 profv, p2v;
    float* prof = (float*)&profv;
    float* p2a  = (float*)&p2v;
    int B[4];

#pragma unroll
    for (int k = 0; k < 4; ++k) {
        int t00 = cc[k + 2];
        int coopC = t00 + up[k + 1] + dn[k + 1] + cc[k + 1] + cc[k + 3];
        int coopN = up[k + 1] + uu[k] + t00 + up[k] + up[k + 2];
        int coopS = dn[k + 1] + t00 + dd[k] + dn[k] + dn[k + 2];
        int coopW = cc[k + 1] + up[k] + dn[k] + cc[k] + t00;
        int coopE = cc[k + 3] + up[k + 2] + dn[k + 2] + t00 + cc[k + 4];

        float dC = dprof(coopC), dN = dprof(coopN), dS = dprof(coopS),
              dW = dprof(coopW), dE = dprof(coopE);
        float cC = __fsub_rn(dC, 1.0f), cN = __fsub_rn(dN, 1.0f),
              cS = __fsub_rn(dS, 1.0f), cW = __fsub_rn(dW, 1.0f),
              cE = __fsub_rn(dE, 1.0f);
        // _neighbor5: ((((center + up) + down) + left) + right)
        float c5 = __fadd_rn(__fadd_rn(__fadd_rn(__fadd_rn(cC, cN), cS), cW), cE);
        float d5 = __fadd_rn(__fadd_rn(__fadd_rn(__fadd_rn(dC, dN), dS), dW), dE);
        float profit = t00 ? c5 : d5;
        prof[k] = profit;

        float qn; int Bact;
        qstep(t00, q[k], trx[k], try_[k], profit, qn, Bact);
        p2a[k] = qn;
        B[k] = Bact;
        float4 qo = q[k];
        if (t00 == 0) { if (Bact == 0) qo.x = qn; else qo.y = qn; }
        else          { if (Bact == 0) qo.z = qn; else qo.w = qn; }
        ((float4*)outQ)[n0 + k] = qo;
    }
    ((float4*)outP)[t4] = profv;
    if (use_ws) {
        ((float4*)p2w)[t4] = p2v;
        uchar4 b4 = make_uchar4((unsigned char)B[0], (unsigned char)B[1],
                                (unsigned char)B[2], (unsigned char)B[3]);
        *(uchar4*)(Bw + (size_t)n0) = b4;
    }
}

// ---------- kernel 2 (ws path): fermi imitation, 4 cells/thread ----------

__device__ __forceinline__ int neigh_idx(int n, int d) {
    int i = n >> LSHIFT, j = n & LMASK;
    // rolls: 0:(+1,ax1)->(i,j-1) left; 1:(-1,ax1)->(i,j+1) right;
    //        2:(+1,ax0)->(i-1,j) up;   3:(-1,ax0)->(i+1,j) down
    int ni = i, nj = j;
    if (d == 0)      nj = (j - 1) & LMASK;
    else if (d == 1) nj = (j + 1) & LMASK;
    else if (d == 2) ni = (i - 1) & LMASK;
    else             ni = (i + 1) & LMASK;
    return (ni << LSHIFT) | nj;
}

__global__ __launch_bounds__(256) void k_fermi_ws(
    const int* __restrict__ type, const int* __restrict__ dir,
    const float* __restrict__ lp, const float* __restrict__ p2w,
    const unsigned char* __restrict__ Bw, float* __restrict__ outT)
{
    int t4 = blockIdx.x * 256 + threadIdx.x;
    int n0 = t4 << 2;
    int4   d4  = ((const int4*)dir)[t4];
    float4 l4  = ((const float4*)lp)[t4];
    int4   ty4 = ((const int4*)type)[t4];
    float4 pc4 = ((const float4*)p2w)[t4];
    int dd[4] = {d4.x, d4.y, d4.z, d4.w};
    int tt[4] = {ty4.x, ty4.y, ty4.z, ty4.w};
    float ll[4] = {l4.x, l4.y, l4.z, l4.w};
    float pp[4] = {pc4.x, pc4.y, pc4.z, pc4.w};
    float4 outv;
    float* ov = (float*)&outv;
#pragma unroll
    for (int k = 0; k < 4; ++k) {
        int nn = neigh_idx(n0 + k, dd[k]);
        double pc = (double)pp[k];
        double pn = (double)p2w[nn];
        // W = sigmoid((pn-pc)/0.5) = 1/(1+exp(2*(pc-pn))), double (near-true)
        double W = 1.0 / (1.0 + exp((pc - pn) * 2.0));
        int tsel = ((double)ll[k] <= W) ? (int)Bw[nn] : tt[k];
        ov[k] = (float)tsel;
    }
    ((float4*)outT)[t4] = outv;
}

// ---------- kernel 2 (stateless fallback): recompute q_new/B per cell ----------

__global__ __launch_bounds__(256) void k_fermi_rc(
    const int* __restrict__ type, const int* __restrict__ dir,
    const float* __restrict__ lp, const float* __restrict__ Q,
    const float* __restrict__ tie, const float* __restrict__ outP,
    float* __restrict__ outT)
{
    int n = blockIdx.x * 256 + threadIdx.x;
    int nn = neigh_idx(n, dir[n]);
    float qnc, qnn; int Bc, Bn;
    {
        int A = type[n];
        float4 q = ((const float4*)Q)[n];
        float2 tr = ((const float2*)tie)[n];
        qstep(A, q, tr.x, tr.y, outP[n], qnc, Bc);
    }
    {
        int A = type[nn];
        float4 q = ((const float4*)Q)[nn];
        float2 tr = ((const float2*)tie)[nn];
        qstep(A, q, tr.x, tr.y, outP[nn], qnn, Bn);
    }
    double W = 1.0 / (1.0 + exp(((double)qnc - (double)qnn) * 2.0));
    float l = lp[n];
    int tsel = ((double)l <= W) ? Bn : type[n];
    outT[n] = (float)tsel;
}

// ---------- host ----------

extern "C" void kernel_launch(void* const* d_in, const int* in_sizes, int n_in,
                              void* d_out, int out_size, void* d_ws, size_t ws_size,
                              hipStream_t stream) {
    const int*   type = (const int*)d_in[0];
    const float* Q    = (const float*)d_in[1];
    const float* tie  = (const float*)d_in[2];
    // d_in[3] random_type and d_in[4] eps_rand are dead: eps_rand >= -1 always
    const int*   dir  = (const int*)d_in[5];
    const float* lp   = (const float*)d_in[6];

    float* out  = (float*)d_out;
    float* outT = out;                       // [N]  type_t2
    float* outQ = out + (size_t)NTOT;        // [4N] Q_new
    float* outP = out + (size_t)NTOT * 5;    // [N]  profit

    size_t need = (size_t)NTOT * 5;          // p2 (4N bytes) + B (N bytes)
    int use_ws = (ws_size >= need) ? 1 : 0;
    float* p2w = (float*)d_ws;
    unsigned char* Bw = (unsigned char*)d_ws + (size_t)NTOT * 4;

    dim3 blk(256), grd4(NTOT / 4 / 256), grd(NTOT / 256);
    hipLaunchKernelGGL(k_payoff_q, grd4, blk, 0, stream,
                       type, Q, tie, outQ, outP,
                       use_ws ? p2w : nullptr, use_ws ? Bw : nullptr, use_ws);
    if (use_ws) {
        hipLaunchKernelGGL(k_fermi_ws, grd4, blk, 0, stream,
                           type, dir, lp, p2w, Bw, outT);
    } else {
        hipLaunchKernelGGL(k_fermi_rc, grd, blk, 0, stream,
                           type, dir, lp, Q, tie, outP, outT);
    }
}

// Round 3
// 64.810 us; speedup vs baseline: 1.1738x; 1.1738x over previous
//
#include <hip/hip_runtime.h>
#include <math.h>

#define LL 2048
#define LSHIFT 11
#define LMASK 2047
#define NTOT (LL * LL)

// d_profit = fl(fl(coop/5)*3.8).  For coop in 0..5, fl(coop/5) == coop*0.2f
// bit-exactly (verified case-by-case), so two mults replace the divide.
__device__ __forceinline__ float dprof(int coop) {
    return __fmul_rn(__fmul_rn((float)coop, 0.2f), 3.8f);
}

// greedy action + q_new chain, exact per-op f32 to match reference
__device__ __forceinline__ void qstep(int A, float4 q, float trx, float try_,
                                      float profit, float& qn, int& Bact) {
    float qa0 = A ? q.z : q.x;
    float qa1 = A ? q.w : q.y;
    float mx = fmaxf(qa0, qa1);
    float v0 = __fadd_rn(qa0 == mx ? 1.0f : -1.0e9f, trx);
    float v1 = __fadd_rn(qa1 == mx ? 1.0f : -1.0e9f, try_);
    Bact = (v1 > v0) ? 1 : 0;   // argmax, first occurrence on ties
    // EPSILON = -1.0, eps_rand in [0,1) -> eps_mask always true -> B = greedy
    float qb0 = Bact ? q.z : q.x;
    float qb1 = Bact ? q.w : q.y;
    float mn = fmaxf(qb0, qb1);                 // max_a' Q_old[n, B, a']
    float qold = A ? (Bact ? q.w : q.z) : (Bact ? q.y : q.x);
    float a1 = __fmul_rn(0.8f, mn);
    float a2 = __fadd_rn(profit, a1);
    float a3 = __fsub_rn(a2, qold);
    float a4 = __fmul_rn(0.8f, a3);
    qn = __fadd_rn(qold, a4);
}

// ---------- kernel 1: payoff stencil + greedy + Q update ----------
// 1 cell/thread (coalesced float streams); type halo staged in LDS.

#define TROWS 5
#define TCOLS 272   // LDS cols cover global cols j0-8 .. j0+263

__global__ __launch_bounds__(256) void k_payoff_q(
    const int* __restrict__ type, const float* __restrict__ Q,
    const float* __restrict__ tie, float* __restrict__ outQ,
    float* __restrict__ outP, float* __restrict__ p2w,
    unsigned char* __restrict__ pb, int use_ws)
{
    __shared__ int ty[TROWS][TCOLS];            // 5.3 KB
    int bi = blockIdx.x;
    int i  = bi >> 3;                           // row
    int j0 = (bi & 7) << 8;                     // col base (multiple of 256)
    int t  = threadIdx.x;
    int n  = (i << LSHIFT) | (j0 + t);

    // issue streaming loads first; latency hides under LDS staging + barrier
    float4 q  = ((const float4*)Q)[n];
    float2 tr = ((const float2*)tie)[n];

    // stage 5 rows x 68 int4 (= 340 int4) of the type halo, coalesced
    const int4* T4 = (const int4*)type;
#pragma unroll
    for (int pass = 0; pass < 2; ++pass) {
        int ll = t + pass * 256;
        if (ll < 340) {
            int rr = ll / 68;                   // 0..4
            int cidx = ll - rr * 68;            // 0..67
            int r = (i - 2 + rr) & LMASK;
            int c = (j0 - 8 + (cidx << 2)) & LMASK;
            int4 v = T4[((r << LSHIFT) | c) >> 2];
            *(int4*)&ty[rr][cidx << 2] = v;
        }
    }
    __syncthreads();

    int jc = t + 8;                             // LDS col of this cell
    int t00 = ty[2][jc];
    int tW  = ty[2][jc - 1], tE  = ty[2][jc + 1];
    int tWW = ty[2][jc - 2], tEE = ty[2][jc + 2];
    int tN  = ty[1][jc], tNW = ty[1][jc - 1], tNE = ty[1][jc + 1];
    int tS  = ty[3][jc], tSW = ty[3][jc - 1], tSE = ty[3][jc + 1];
    int tNN = ty[0][jc], tSS = ty[4][jc];

    int coopC = t00 + tN + tS + tW + tE;
    int coopN = tN + tNN + t00 + tNW + tNE;
    int coopS = tS + t00 + tSS + tSW + tSE;
    int coopW = tW + tNW + tSW + tWW + t00;
    int coopE = tE + tNE + tSE + t00 + tEE;

    float dC = dprof(coopC), dN = dprof(coopN), dS = dprof(coopS),
          dW = dprof(coopW), dE = dprof(coopE);
    float cC = __fsub_rn(dC, 1.0f), cN = __fsub_rn(dN, 1.0f),
          cS = __fsub_rn(dS, 1.0f), cW = __fsub_rn(dW, 1.0f),
          cE = __fsub_rn(dE, 1.0f);
    // _neighbor5: ((((center + up) + down) + left) + right)
    float c5 = __fadd_rn(__fadd_rn(__fadd_rn(__fadd_rn(cC, cN), cS), cW), cE);
    float d5 = __fadd_rn(__fadd_rn(__fadd_rn(__fadd_rn(dC, dN), dS), dW), dE);
    float profit = t00 ? c5 : d5;

    float qn; int Bact;
    qstep(t00, q, tr.x, tr.y, profit, qn, Bact);

    float4 qo = q;
    if (t00 == 0) { if (Bact == 0) qo.x = qn; else qo.y = qn; }
    else          { if (Bact == 0) qo.z = qn; else qo.w = qn; }
    ((float4*)outQ)[n] = qo;
    outP[n] = profit;
    if (use_ws) {
        p2w[n] = qn;
        pb[n] = (unsigned char)(Bact | (t00 << 1));   // bit0=B, bit1=type
    }
}

// ---------- kernel 2 (ws path): fermi imitation, 4 cells/thread ----------

__device__ __forceinline__ int neigh_idx(int n, int d) {
    int i = n >> LSHIFT, j = n & LMASK;
    // rolls: 0:(+1,ax1)->(i,j-1) left; 1:(-1,ax1)->(i,j+1) right;
    //        2:(+1,ax0)->(i-1,j) up;   3:(-1,ax0)->(i+1,j) down
    int ni = i, nj = j;
    if (d == 0)      nj = (j - 1) & LMASK;
    else if (d == 1) nj = (j + 1) & LMASK;
    else if (d == 2) ni = (i - 1) & LMASK;
    else             ni = (i + 1) & LMASK;
    return (ni << LSHIFT) | nj;
}

__global__ __launch_bounds__(256) void k_fermi_ws(
    const int* __restrict__ dir, const float* __restrict__ lp,
    const float* __restrict__ p2w, const unsigned char* __restrict__ pb,
    float* __restrict__ outT)
{
    int t4 = blockIdx.x * 256 + threadIdx.x;
    int n0 = t4 << 2;
    int4   d4  = ((const int4*)dir)[t4];
    float4 l4  = ((const float4*)lp)[t4];
    float4 pc4 = ((const float4*)p2w)[t4];
    uchar4 pbc = *(const uchar4*)(pb + (size_t)n0);
    int dd[4] = {d4.x, d4.y, d4.z, d4.w};
    int tt[4] = {pbc.x >> 1, pbc.y >> 1, pbc.z >> 1, pbc.w >> 1};
    float ll[4] = {l4.x, l4.y, l4.z, l4.w};
    float pp[4] = {pc4.x, pc4.y, pc4.z, pc4.w};
    float4 outv;
    float* ov = (float*)&outv;
#pragma unroll
    for (int k = 0; k < 4; ++k) {
        int nn = neigh_idx(n0 + k, dd[k]);
        double pc = (double)pp[k];
        double pn = (double)p2w[nn];
        // W = sigmoid((pn-pc)/0.5) = 1/(1+exp(2*(pc-pn))), double (near-true)
        double W = 1.0 / (1.0 + exp((pc - pn) * 2.0));
        int tsel = ((double)ll[k] <= W) ? (pb[nn] & 1) : tt[k];
        ov[k] = (float)tsel;
    }
    ((float4*)outT)[t4] = outv;
}

// ---------- kernel 2 (stateless fallback): recompute q_new/B per cell ----------

__global__ __launch_bounds__(256) void k_fermi_rc(
    const int* __restrict__ type, const int* __restrict__ dir,
    const float* __restrict__ lp, const float* __restrict__ Q,
    const float* __restrict__ tie, const float* __restrict__ outP,
    float* __restrict__ outT)
{
    int n = blockIdx.x * 256 + threadIdx.x;
    int nn = neigh_idx(n, dir[n]);
    float qnc, qnn; int Bc, Bn;
    {
        int A = type[n];
        float4 q = ((const float4*)Q)[n];
        float2 tr = ((const float2*)tie)[n];
        qstep(A, q, tr.x, tr.y, outP[n], qnc, Bc);
    }
    {
        int A = type[nn];
        float4 q = ((const float4*)Q)[nn];
        float2 tr = ((const float2*)tie)[nn];
        qstep(A, q, tr.x, tr.y, outP[nn], qnn, Bn);
    }
    double W = 1.0 / (1.0 + exp(((double)qnc - (double)qnn) * 2.0));
    float l = lp[n];
    int tsel = ((double)l <= W) ? Bn : type[n];
    outT[n] = (float)tsel;
}

// ---------- host ----------

extern "C" void kernel_launch(void* const* d_in, const int* in_sizes, int n_in,
                              void* d_out, int out_size, void* d_ws, size_t ws_size,
                              hipStream_t stream) {
    const int*   type = (const int*)d_in[0];
    const float* Q    = (const float*)d_in[1];
    const float* tie  = (const float*)d_in[2];
    // d_in[3] random_type and d_in[4] eps_rand are dead: eps_rand >= -1 always
    const int*   dir  = (const int*)d_in[5];
    const float* lp   = (const float*)d_in[6];

    float* out  = (float*)d_out;
    float* outT = out;                       // [N]  type_t2
    float* outQ = out + (size_t)NTOT;        // [4N] Q_new
    float* outP = out + (size_t)NTOT * 5;    // [N]  profit

    size_t need = (size_t)NTOT * 5;          // p2 (4N bytes) + packed byte (N)
    int use_ws = (ws_size >= need) ? 1 : 0;
    float* p2w = (float*)d_ws;
    unsigned char* pb = (unsigned char*)d_ws + (size_t)NTOT * 4;

    dim3 blk(256), grd(NTOT / 256), grd4(NTOT / 4 / 256);
    hipLaunchKernelGGL(k_payoff_q, grd, blk, 0, stream,
                       type, Q, tie, outQ, outP,
                       use_ws ? p2w : nullptr, use_ws ? pb : nullptr, use_ws);
    if (use_ws) {
        hipLaunchKernelGGL(k_fermi_ws, grd4, blk, 0, stream,
                           dir, lp, p2w, pb, outT);
    } else {
        hipLaunchKernelGGL(k_fermi_rc, grd, blk, 0, stream,
                           type, dir, lp, Q, tie, outP, outT);
    }
}

// Round 4
// 63.861 us; speedup vs baseline: 1.1912x; 1.0149x over previous
//
#include <hip/hip_runtime.h>
#include <math.h>

#define LL 2048
#define LSHIFT 11
#define LMASK 2047
#define NTOT (LL * LL)

// d_profit = fl(fl(coop/5)*3.8).  For coop in 0..5, fl(coop/5) == coop*0.2f
// bit-exactly (verified case-by-case), so two mults replace the divide.
__device__ __forceinline__ float dprof(int coop) {
    return __fmul_rn(__fmul_rn((float)coop, 0.2f), 3.8f);
}

// greedy action + q_new chain, exact per-op f32 to match reference
__device__ __forceinline__ void qstep(int A, float4 q, float trx, float try_,
                                      float profit, float& qn, int& Bact) {
    float qa0 = A ? q.z : q.x;
    float qa1 = A ? q.w : q.y;
    float mx = fmaxf(qa0, qa1);
    float v0 = __fadd_rn(qa0 == mx ? 1.0f : -1.0e9f, trx);
    float v1 = __fadd_rn(qa1 == mx ? 1.0f : -1.0e9f, try_);
    Bact = (v1 > v0) ? 1 : 0;   // argmax, first occurrence on ties
    // EPSILON = -1.0, eps_rand in [0,1) -> eps_mask always true -> B = greedy
    float qb0 = Bact ? q.z : q.x;
    float qb1 = Bact ? q.w : q.y;
    float mn = fmaxf(qb0, qb1);                 // max_a' Q_old[n, B, a']
    float qold = A ? (Bact ? q.w : q.z) : (Bact ? q.y : q.x);
    float a1 = __fmul_rn(0.8f, mn);
    float a2 = __fadd_rn(profit, a1);
    float a3 = __fsub_rn(a2, qold);
    float a4 = __fmul_rn(0.8f, a3);
    qn = __fadd_rn(qold, a4);
}

// ---------- kernel 1: payoff stencil + greedy + Q update ----------
// 4 rows x 256 cols per block, 4 cells per thread COLUMN-wise:
// thread t owns column j0+t in 4 consecutive rows -> every global stream
// (Q, tie, outQ, outP, p2w, pb) stays perfectly lane-coalesced, and each
// thread has 4 independent load->compute->store chains (4x MLP).

#define TROWS 8     // 4 cell rows + 2 halo above + 2 below
#define TCOLS 272   // cols j0-8 .. j0+263

__global__ __launch_bounds__(256) void k_payoff_q(
    const int* __restrict__ type, const float* __restrict__ Q,
    const float* __restrict__ tie, float* __restrict__ outQ,
    float* __restrict__ outP, float* __restrict__ p2w,
    unsigned char* __restrict__ pb, int use_ws)
{
    __shared__ int ty[TROWS][TCOLS];            // 8.7 KB
    int bi = blockIdx.x;
    int i0 = (bi >> 3) << 2;                    // first of 4 rows
    int j0 = (bi & 7) << 8;                     // col base (multiple of 256)
    int t  = threadIdx.x;

    // issue all streaming loads first; latency hides under LDS staging
    const float4* Q4 = (const float4*)Q;
    const float2* T2 = (const float2*)tie;
    float4 q[4];
    float2 tr[4];
#pragma unroll
    for (int k = 0; k < 4; ++k) {
        int n = ((i0 + k) << LSHIFT) | (j0 + t);
        q[k]  = Q4[n];
        tr[k] = T2[n];
    }

    // stage 8 rows x 68 int4 (= 544 int4) of the type halo, coalesced
    const int4* T4 = (const int4*)type;
    for (int ll = t; ll < 68 * TROWS; ll += 256) {
        int rr = ll / 68;
        int cidx = ll - rr * 68;
        int r = (i0 - 2 + rr) & LMASK;
        int c = (j0 - 8 + (cidx << 2)) & LMASK;
        *(int4*)&ty[rr][cidx << 2] = T4[((r << LSHIFT) | c) >> 2];
    }
    __syncthreads();

    int jc = t + 8;                             // LDS col of this column
#pragma unroll
    for (int k = 0; k < 4; ++k) {
        int cr = k + 2;                         // LDS row of cell (i0+k)
        int t00 = ty[cr][jc];
        int tW  = ty[cr][jc - 1], tE  = ty[cr][jc + 1];
        int tWW = ty[cr][jc - 2], tEE = ty[cr][jc + 2];
        int tN  = ty[cr - 1][jc], tNW = ty[cr - 1][jc - 1], tNE = ty[cr - 1][jc + 1];
        int tS  = ty[cr + 1][jc], tSW = ty[cr + 1][jc - 1], tSE = ty[cr + 1][jc + 1];
        int tNN = ty[cr - 2][jc], tSS = ty[cr + 2][jc];

        int coopC = t00 + tN + tS + tW + tE;
        int coopN = tN + tNN + t00 + tNW + tNE;
        int coopS = tS + t00 + tSS + tSW + tSE;
        int coopW = tW + tNW + tSW + tWW + t00;
        int coopE = tE + tNE + tSE + t00 + tEE;

        float dC = dprof(coopC), dN = dprof(coopN), dS = dprof(coopS),
              dW = dprof(coopW), dE = dprof(coopE);
        float cC = __fsub_rn(dC, 1.0f), cN = __fsub_rn(dN, 1.0f),
              cS = __fsub_rn(dS, 1.0f), cW = __fsub_rn(dW, 1.0f),
              cE = __fsub_rn(dE, 1.0f);
        // _neighbor5: ((((center + up) + down) + left) + right)
        float c5 = __fadd_rn(__fadd_rn(__fadd_rn(__fadd_rn(cC, cN), cS), cW), cE);
        float d5 = __fadd_rn(__fadd_rn(__fadd_rn(__fadd_rn(dC, dN), dS), dW), dE);
        float profit = t00 ? c5 : d5;

        float qn; int Bact;
        qstep(t00, q[k], tr[k].x, tr[k].y, profit, qn, Bact);

        float4 qo = q[k];
        if (t00 == 0) { if (Bact == 0) qo.x = qn; else qo.y = qn; }
        else          { if (Bact == 0) qo.z = qn; else qo.w = qn; }

        int n = ((i0 + k) << LSHIFT) | (j0 + t);
        ((float4*)outQ)[n] = qo;
        outP[n] = profit;
        if (use_ws) {
            p2w[n] = qn;
            pb[n] = (unsigned char)(Bact | (t00 << 1));   // bit0=B, bit1=type
        }
    }
}

// ---------- kernel 2 (ws path): fermi imitation, 4 cells/thread ----------

__device__ __forceinline__ int neigh_idx(int n, int d) {
    int i = n >> LSHIFT, j = n & LMASK;
    // rolls: 0:(+1,ax1)->(i,j-1) left; 1:(-1,ax1)->(i,j+1) right;
    //        2:(+1,ax0)->(i-1,j) up;   3:(-1,ax0)->(i+1,j) down
    int ni = i, nj = j;
    if (d == 0)      nj = (j - 1) & LMASK;
    else if (d == 1) nj = (j + 1) & LMASK;
    else if (d == 2) ni = (i - 1) & LMASK;
    else             ni = (i + 1) & LMASK;
    return (ni << LSHIFT) | nj;
}

__global__ __launch_bounds__(256) void k_fermi_ws(
    const int* __restrict__ dir, const float* __restrict__ lp,
    const float* __restrict__ p2w, const unsigned char* __restrict__ pb,
    float* __restrict__ outT)
{
    int t4 = blockIdx.x * 256 + threadIdx.x;
    int n0 = t4 << 2;
    int4   d4  = ((const int4*)dir)[t4];
    float4 l4  = ((const float4*)lp)[t4];
    float4 pc4 = ((const float4*)p2w)[t4];
    uchar4 pbc = *(const uchar4*)(pb + (size_t)n0);
    int dd[4] = {d4.x, d4.y, d4.z, d4.w};
    int tt[4] = {pbc.x >> 1, pbc.y >> 1, pbc.z >> 1, pbc.w >> 1};
    float ll[4] = {l4.x, l4.y, l4.z, l4.w};
    float pp[4] = {pc4.x, pc4.y, pc4.z, pc4.w};
    float4 outv;
    float* ov = (float*)&outv;
#pragma unroll
    for (int k = 0; k < 4; ++k) {
        int nn = neigh_idx(n0 + k, dd[k]);
        double pc = (double)pp[k];
        double pn = (double)p2w[nn];
        // W = sigmoid((pn-pc)/0.5) = 1/(1+exp(2*(pc-pn))), double (near-true)
        double W = 1.0 / (1.0 + exp((pc - pn) * 2.0));
        int tsel = ((double)ll[k] <= W) ? (pb[nn] & 1) : tt[k];
        ov[k] = (float)tsel;
    }
    ((float4*)outT)[t4] = outv;
}

// ---------- kernel 2 (stateless fallback): recompute q_new/B per cell ----------

__global__ __launch_bounds__(256) void k_fermi_rc(
    const int* __restrict__ type, const int* __restrict__ dir,
    const float* __restrict__ lp, const float* __restrict__ Q,
    const float* __restrict__ tie, const float* __restrict__ outP,
    float* __restrict__ outT)
{
    int n = blockIdx.x * 256 + threadIdx.x;
    int nn = neigh_idx(n, dir[n]);
    float qnc, qnn; int Bc, Bn;
    {
        int A = type[n];
        float4 q = ((const float4*)Q)[n];
        float2 tr = ((const float2*)tie)[n];
        qstep(A, q, tr.x, tr.y, outP[n], qnc, Bc);
    }
    {
        int A = type[nn];
        float4 q = ((const float4*)Q)[nn];
        float2 tr = ((const float2*)tie)[nn];
        qstep(A, q, tr.x, tr.y, outP[nn], qnn, Bn);
    }
    double W = 1.0 / (1.0 + exp(((double)qnc - (double)qnn) * 2.0));
    float l = lp[n];
    int tsel = ((double)l <= W) ? Bn : type[n];
    outT[n] = (float)tsel;
}

// ---------- host ----------

extern "C" void kernel_launch(void* const* d_in, const int* in_sizes, int n_in,
                              void* d_out, int out_size, void* d_ws, size_t ws_size,
                              hipStream_t stream) {
    const int*   type = (const int*)d_in[0];
    const float* Q    = (const float*)d_in[1];
    const float* tie  = (const float*)d_in[2];
    // d_in[3] random_type and d_in[4] eps_rand are dead: eps_rand >= -1 always
    const int*   dir  = (const int*)d_in[5];
    const float* lp   = (const float*)d_in[6];

    float* out  = (float*)d_out;
    float* outT = out;                       // [N]  type_t2
    float* outQ = out + (size_t)NTOT;        // [4N] Q_new
    float* outP = out + (size_t)NTOT * 5;    // [N]  profit

    size_t need = (size_t)NTOT * 5;          // p2 (4N bytes) + packed byte (N)
    int use_ws = (ws_size >= need) ? 1 : 0;
    float* p2w = (float*)d_ws;
    unsigned char* pb = (unsigned char*)d_ws + (size_t)NTOT * 4;

    dim3 blk(256), grd4r(NTOT / 4 / 256), grd(NTOT / 256), grd4(NTOT / 4 / 256);
    hipLaunchKernelGGL(k_payoff_q, grd4r, blk, 0, stream,
                       type, Q, tie, outQ, outP,
                       use_ws ? p2w : nullptr, use_ws ? pb : nullptr, use_ws);
    if (use_ws) {
        hipLaunchKernelGGL(k_fermi_ws, grd4, blk, 0, stream,
                           dir, lp, p2w, pb, outT);
    } else {
        hipLaunchKernelGGL(k_fermi_rc, grd, blk, 0, stream,
                           type, dir, lp, Q, tie, outP, outT);
    }
}

// Round 5
// 47.855 us; speedup vs baseline: 1.5897x; 1.3345x over previous
//
#include <hip/hip_runtime.h>
#include <math.h>

#define LL 2048
#define LSHIFT 11
#define LMASK 2047
#define NTOT (LL * LL)

typedef float f32x4 __attribute__((ext_vector_type(4)));
typedef float f32x2 __attribute__((ext_vector_type(2)));

#define TROWS 7     // rows i-3 .. i+3 (own stencil +-2, neighbor's stencil +-3)
#define TCOLS 272   // cols j0-8 .. j0+263

// d_profit = fl(fl(coop/5)*3.8).  For coop in 0..5, fl(coop/5) == coop*0.2f
// bit-exactly (verified case-by-case), so two mults replace the divide.
__device__ __forceinline__ float dprof(int coop) {
    return __fmul_rn(__fmul_rn((float)coop, 0.2f), 3.8f);
}

// plus-of-plus stencil profit for LDS cell (cr, cc); exact per-op f32
__device__ __forceinline__ float cell_profit(const int ty[TROWS][TCOLS],
                                             int cr, int cc, int& t00o) {
    int t00 = ty[cr][cc];
    int tW  = ty[cr][cc - 1], tE  = ty[cr][cc + 1];
    int tWW = ty[cr][cc - 2], tEE = ty[cr][cc + 2];
    int tN  = ty[cr - 1][cc], tNW = ty[cr - 1][cc - 1], tNE = ty[cr - 1][cc + 1];
    int tS  = ty[cr + 1][cc], tSW = ty[cr + 1][cc - 1], tSE = ty[cr + 1][cc + 1];
    int tNN = ty[cr - 2][cc], tSS = ty[cr + 2][cc];

    int coopC = t00 + tN + tS + tW + tE;
    int coopN = tN + tNN + t00 + tNW + tNE;
    int coopS = tS + t00 + tSS + tSW + tSE;
    int coopW = tW + tNW + tSW + tWW + t00;
    int coopE = tE + tNE + tSE + t00 + tEE;

    float dC = dprof(coopC), dN = dprof(coopN), dS = dprof(coopS),
          dW = dprof(coopW), dE = dprof(coopE);
    float cC = __fsub_rn(dC, 1.0f), cN = __fsub_rn(dN, 1.0f),
          cS = __fsub_rn(dS, 1.0f), cW = __fsub_rn(dW, 1.0f),
          cE = __fsub_rn(dE, 1.0f);
    // _neighbor5: ((((center + up) + down) + left) + right)
    float c5 = __fadd_rn(__fadd_rn(__fadd_rn(__fadd_rn(cC, cN), cS), cW), cE);
    float d5 = __fadd_rn(__fadd_rn(__fadd_rn(__fadd_rn(dC, dN), dS), dW), dE);
    t00o = t00;
    return t00 ? c5 : d5;
}

// greedy action + q_new chain, exact per-op f32 to match reference
__device__ __forceinline__ void qstep(int A, f32x4 q, float trx, float try_,
                                      float profit, float& qn, int& Bact) {
    float qa0 = A ? q.z : q.x;
    float qa1 = A ? q.w : q.y;
    float mx = fmaxf(qa0, qa1);
    float v0 = __fadd_rn(qa0 == mx ? 1.0f : -1.0e9f, trx);
    float v1 = __fadd_rn(qa1 == mx ? 1.0f : -1.0e9f, try_);
    Bact = (v1 > v0) ? 1 : 0;   // argmax, first occurrence on ties
    // EPSILON = -1.0, eps_rand in [0,1) -> eps_mask always true -> B = greedy
    float qb0 = Bact ? q.z : q.x;
    float qb1 = Bact ? q.w : q.y;
    float mn = fmaxf(qb0, qb1);                 // max_a' Q_old[n, B, a']
    float qold = A ? (Bact ? q.w : q.z) : (Bact ? q.y : q.x);
    float a1 = __fmul_rn(0.8f, mn);
    float a2 = __fadd_rn(profit, a1);
    float a3 = __fsub_rn(a2, qold);
    float a4 = __fmul_rn(0.8f, a3);
    qn = __fadd_rn(qold, a4);
}

// ---------- fused kernel: stencil + greedy + Q update + fermi ----------
// One cell per thread, perfectly coalesced streams.  The fermi step needs the
// SELECTED neighbor's q_new and B; both are pure functions of the inputs, so
// recompute them locally (bit-identical to the neighbor thread's own values).
// No workspace: working set = inputs 144 MB + outputs 100 MB < 256 MB L3.

__global__ __launch_bounds__(256) void k_fused(
    const int* __restrict__ type, const float* __restrict__ Q,
    const float* __restrict__ tie, const int* __restrict__ dir,
    const float* __restrict__ lp, float* __restrict__ outT,
    float* __restrict__ outQ, float* __restrict__ outP)
{
    __shared__ int ty[TROWS][TCOLS];            // 7.4 KB
    int bi = blockIdx.x;
    int i  = bi >> 3;                           // row
    int j0 = (bi & 7) << 8;                     // col base
    int t  = threadIdx.x;
    int j  = j0 + t;
    int n  = (i << LSHIFT) | j;

    // own-cell streaming loads first; latency hides under staging
    int   d  = dir[n];
    float l  = lp[n];
    f32x4 q  = ((const f32x4*)Q)[n];
    f32x2 tr = ((const f32x2*)tie)[n];

    // stage 7 rows x 68 int4 of the type halo, coalesced
    const int4* T4 = (const int4*)type;
    for (int ll = t; ll < 68 * TROWS; ll += 256) {
        int rr = ll / 68;
        int cidx = ll - rr * 68;
        int r = (i - 3 + rr) & LMASK;
        int c = (j0 - 8 + (cidx << 2)) & LMASK;
        *(int4*)&ty[rr][cidx << 2] = T4[((r << LSHIFT) | c) >> 2];
    }

    // selected neighbor (rolls: 0 left, 1 right, 2 up, 3 down)
    int drow = (d == 2) ? -1 : ((d == 3) ? 1 : 0);
    int dcol = (d == 0) ? -1 : ((d == 1) ? 1 : 0);
    int nn = (((i + drow) & LMASK) << LSHIFT) | ((j + dcol) & LMASK);
    f32x4 qn4 = ((const f32x4*)Q)[nn];          // gather, L2/L3-hot
    f32x2 trn = ((const f32x2*)tie)[nn];

    __syncthreads();

    int jc = t + 8;                             // own LDS col, row 3
    int t00;
    float profitC = cell_profit(ty, 3, jc, t00);
    float qnC; int BC;
    qstep(t00, q, tr.x, tr.y, profitC, qnC, BC);

    int tn0;
    float profitN = cell_profit(ty, 3 + drow, jc + dcol, tn0);
    float qnN; int BN;
    qstep(tn0, qn4, trn.x, trn.y, profitN, qnN, BN);

    // W = sigmoid((pn-pc)/0.5) = 1/(1+exp(2*(pc-pn))), double (near-true)
    double W = 1.0 / (1.0 + exp(((double)qnC - (double)qnN) * 2.0));
    int tsel = ((double)l <= W) ? BN : t00;

    f32x4 qo = q;
    if (t00 == 0) { if (BC == 0) qo.x = qnC; else qo.y = qnC; }
    else          { if (BC == 0) qo.z = qnC; else qo.w = qnC; }

    // outputs are write-once per launch and never re-read: nontemporal so they
    // don't evict the L3-resident inputs
    __builtin_nontemporal_store(qo, (f32x4*)outQ + n);
    __builtin_nontemporal_store(profitC, outP + n);
    __builtin_nontemporal_store((float)tsel, outT + n);
}

// ---------- host ----------

extern "C" void kernel_launch(void* const* d_in, const int* in_sizes, int n_in,
                              void* d_out, int out_size, void* d_ws, size_t ws_size,
                              hipStream_t stream) {
    const int*   type = (const int*)d_in[0];
    const float* Q    = (const float*)d_in[1];
    const float* tie  = (const float*)d_in[2];
    // d_in[3] random_type and d_in[4] eps_rand are dead: eps_rand >= -1 always
    const int*   dir  = (const int*)d_in[5];
    const float* lp   = (const float*)d_in[6];

    float* out  = (float*)d_out;
    float* outT = out;                       // [N]  type_t2
    float* outQ = out + (size_t)NTOT;        // [4N] Q_new
    float* outP = out + (size_t)NTOT * 5;    // [N]  profit

    dim3 blk(256), grd(NTOT / 256);
    hipLaunchKernelGGL(k_fused, grd, blk, 0, stream,
                       type, Q, tie, dir, lp, outT, outQ, outP);
}

// Round 6
// 40.184 us; speedup vs baseline: 1.8931x; 1.1909x over previous
//
#include <hip/hip_runtime.h>
#include <math.h>

#define LL 2048
#define LSHIFT 11
#define LMASK 2047
#define NTOT (LL * LL)

typedef float f32x4 __attribute__((ext_vector_type(4)));
typedef float f32x2 __attribute__((ext_vector_type(2)));

#define TROWS 7     // rows i-3 .. i+3 (own stencil +-2, neighbor's stencil +-3)
#define TCOLS 272   // cols j0-8 .. j0+263

// d_profit = fl(fl(coop/5)*3.8).  For coop in 0..5, fl(coop/5) == coop*0.2f
// bit-exactly (verified case-by-case), so two mults replace the divide.
__device__ __forceinline__ float dprof(int coop) {
    return __fmul_rn(__fmul_rn((float)coop, 0.2f), 3.8f);
}

// plus-of-plus stencil profit for LDS cell (cr, cc); exact per-op f32
__device__ __forceinline__ float cell_profit(const int ty[TROWS][TCOLS],
                                             int cr, int cc, int& t00o) {
    int t00 = ty[cr][cc];
    int tW  = ty[cr][cc - 1], tE  = ty[cr][cc + 1];
    int tWW = ty[cr][cc - 2], tEE = ty[cr][cc + 2];
    int tN  = ty[cr - 1][cc], tNW = ty[cr - 1][cc - 1], tNE = ty[cr - 1][cc + 1];
    int tS  = ty[cr + 1][cc], tSW = ty[cr + 1][cc - 1], tSE = ty[cr + 1][cc + 1];
    int tNN = ty[cr - 2][cc], tSS = ty[cr + 2][cc];

    int coopC = t00 + tN + tS + tW + tE;
    int coopN = tN + tNN + t00 + tNW + tNE;
    int coopS = tS + t00 + tSS + tSW + tSE;
    int coopW = tW + tNW + tSW + tWW + t00;
    int coopE = tE + tNE + tSE + t00 + tEE;

    float dC = dprof(coopC), dN = dprof(coopN), dS = dprof(coopS),
          dW = dprof(coopW), dE = dprof(coopE);
    float cC = __fsub_rn(dC, 1.0f), cN = __fsub_rn(dN, 1.0f),
          cS = __fsub_rn(dS, 1.0f), cW = __fsub_rn(dW, 1.0f),
          cE = __fsub_rn(dE, 1.0f);
    // _neighbor5: ((((center + up) + down) + left) + right)
    float c5 = __fadd_rn(__fadd_rn(__fadd_rn(__fadd_rn(cC, cN), cS), cW), cE);
    float d5 = __fadd_rn(__fadd_rn(__fadd_rn(__fadd_rn(dC, dN), dS), dW), dE);
    t00o = t00;
    return t00 ? c5 : d5;
}

// greedy action + q_new chain, exact per-op f32 to match reference.
// tie is loaded LAZILY: masked = is_max - (1-is_max)*1e9 with tie in [0,1)
// means tie can only change the argmax when qa0 == qa1 exactly.
__device__ __forceinline__ void qstep(int A, f32x4 q, const f32x2* tie2, int n,
                                      float profit, float& qn, int& Bact) {
    float qa0 = A ? q.z : q.x;
    float qa1 = A ? q.w : q.y;
    int greedy;
    if (qa0 == qa1) {                 // rare: exact tie -> tie_rand decides
        f32x2 tr = tie2[n];
        float v0 = __fadd_rn(1.0f, tr.x);
        float v1 = __fadd_rn(1.0f, tr.y);
        greedy = (v1 > v0) ? 1 : 0;
    } else {
        greedy = (qa1 > qa0) ? 1 : 0; // mask -1e9 loses regardless of tie
    }
    int B = greedy;                   // EPSILON=-1 -> eps_mask always true
    float qb0 = B ? q.z : q.x;
    float qb1 = B ? q.w : q.y;
    float mn = fmaxf(qb0, qb1);       // max_a' Q_old[n, B, a']
    float qold = A ? (B ? q.w : q.z) : (B ? q.y : q.x);
    float a1 = __fmul_rn(0.8f, mn);
    float a2 = __fadd_rn(profit, a1);
    float a3 = __fsub_rn(a2, qold);
    float a4 = __fmul_rn(0.8f, a3);
    qn = __fadd_rn(qold, a4);
    Bact = B;
}

// ---------- fused kernel: stencil + greedy + Q update + fermi ----------

__global__ __launch_bounds__(256) void k_fused(
    const int* __restrict__ type, const float* __restrict__ Q,
    const float* __restrict__ tie, const int* __restrict__ dir,
    const float* __restrict__ lp, float* __restrict__ outT,
    float* __restrict__ outQ, float* __restrict__ outP)
{
    __shared__ int ty[TROWS][TCOLS];            // 7.4 KB
    int bi = blockIdx.x;
    int i  = bi >> 3;                           // row
    int j0 = (bi & 7) << 8;                     // col base
    int t  = threadIdx.x;
    int j  = j0 + t;
    int n  = (i << LSHIFT) | j;

    // own-cell streaming loads first; latency hides under staging
    int   d  = dir[n];
    float l  = lp[n];
    f32x4 q  = ((const f32x4*)Q)[n];

    // stage 7 rows x 68 int4 of the type halo, coalesced
    const int4* T4 = (const int4*)type;
    for (int ll = t; ll < 68 * TROWS; ll += 256) {
        int rr = ll / 68;
        int cidx = ll - rr * 68;
        int r = (i - 3 + rr) & LMASK;
        int c = (j0 - 8 + (cidx << 2)) & LMASK;
        *(int4*)&ty[rr][cidx << 2] = T4[((r << LSHIFT) | c) >> 2];
    }

    // selected neighbor (rolls: 0 left, 1 right, 2 up, 3 down)
    int drow = (d == 2) ? -1 : ((d == 3) ? 1 : 0);
    int dcol = (d == 0) ? -1 : ((d == 1) ? 1 : 0);
    int nn = (((i + drow) & LMASK) << LSHIFT) | ((j + dcol) & LMASK);
    f32x4 qn4 = ((const f32x4*)Q)[nn];          // gather, L2/L3-hot

    __syncthreads();

    const f32x2* tie2 = (const f32x2*)tie;
    int jc = t + 8;                             // own LDS col, row 3
    int t00;
    float profitC = cell_profit(ty, 3, jc, t00);
    float qnC; int BC;
    qstep(t00, q, tie2, n, profitC, qnC, BC);

    int tn0;
    float profitN = cell_profit(ty, 3 + drow, jc + dcol, tn0);
    float qnN; int BN;
    qstep(tn0, qn4, tie2, nn, profitN, qnN, BN);

    // W = sigmoid((pn-pc)/0.5).  Fast f32 path; |W32 - W_f64| < ~3e-6, so a
    // 1e-4 guard band around lp makes the decision provably identical to the
    // f64 formulation; only guard-band lanes take the slow f64 exp.
    float z32 = __fmul_rn(__fsub_rn(qnC, qnN), 2.0f);
    float W32 = 1.0f / (1.0f + __expf(z32));
    int take;
    if (fabsf(l - W32) > 1.0e-4f) {
        take = (l <= W32);
    } else {
        double W = 1.0 / (1.0 + exp(((double)qnC - (double)qnN) * 2.0));
        take = ((double)l <= W);
    }
    int tsel = take ? BN : t00;

    f32x4 qo = q;
    if (t00 == 0) { if (BC == 0) qo.x = qnC; else qo.y = qnC; }
    else          { if (BC == 0) qo.z = qnC; else qo.w = qnC; }

    // outputs are write-once and never re-read: nontemporal so they don't
    // evict the L3-resident inputs
    __builtin_nontemporal_store(qo, (f32x4*)outQ + n);
    __builtin_nontemporal_store(profitC, outP + n);
    __builtin_nontemporal_store((float)tsel, outT + n);
}

// ---------- host ----------

extern "C" void kernel_launch(void* const* d_in, const int* in_sizes, int n_in,
                              void* d_out, int out_size, void* d_ws, size_t ws_size,
                              hipStream_t stream) {
    const int*   type = (const int*)d_in[0];
    const float* Q    = (const float*)d_in[1];
    const float* tie  = (const float*)d_in[2];
    // d_in[3] random_type and d_in[4] eps_rand are dead: eps_rand >= -1 always
    const int*   dir  = (const int*)d_in[5];
    const float* lp   = (const float*)d_in[6];

    float* out  = (float*)d_out;
    float* outT = out;                       // [N]  type_t2
    float* outQ = out + (size_t)NTOT;        // [4N] Q_new
    float* outP = out + (size_t)NTOT * 5;    // [N]  profit

    dim3 blk(256), grd(NTOT / 256);
    hipLaunchKernelGGL(k_fused, grd, blk, 0, stream,
                       type, Q, tie, dir, lp, outT, outQ, outP);
}